// Round 10
// baseline (711.165 us; speedup 1.0000x reference)
//
#include <hip/hip_runtime.h>

#define NNODES 100000
#define NEDGES 1600000
#define NGRAPH 512
#define EPSBN 1e-5f
#define DEGCAP 64    // max in-degree; Binomial tail beyond 64 ~1e-20
#define NBUCK 512    // dst buckets of 256 nodes (391 used)
#define BSH 8
#define BCAP 4864    // per-bucket capacity: mean 4096, sd 64, +12 sigma margin
#define P1_BLOCKS ((NEDGES + 4095)/4096)   // 391
#define GEMM_BLOCKS ((NNODES + 63)/64)     // 1563

typedef unsigned short ushort_t;
typedef unsigned int uint_t;

typedef __attribute__((ext_vector_type(8))) __bf16 bf16x8;
typedef __attribute__((ext_vector_type(4))) float f32x4;
typedef __attribute__((ext_vector_type(2))) uint_t uintx2;

__device__ __forceinline__ float b2f(ushort_t u){ return __uint_as_float(((uint_t)u)<<16); }
// native bf16 convert (RNE) — compiler emits v_cvt_pk_bf16_f32
__device__ __forceinline__ ushort_t f2b(float f){
  union { __bf16 h; ushort_t u; } c;
  c.h = (__bf16)f;
  return c.u;
}
__device__ __forceinline__ uint_t pkbf(float a, float b){
  union { __bf16 h[2]; uint_t u; } c;
  c.h[0] = (__bf16)a; c.h[1] = (__bf16)b;
  return c.u;
}
__device__ __forceinline__ float lo16(uint_t d){ return b2f((ushort_t)(d & 0xffffu)); }
__device__ __forceinline__ float hi16(uint_t d){ return b2f((ushort_t)(d >> 16)); }

__device__ __forceinline__ f32x4 mfma_bf16(bf16x8 a, bf16x8 b, f32x4 c){
  return __builtin_amdgcn_mfma_f32_16x16x32_bf16(a, b, c, 0, 0, 0);
}

union Frag8 { ushort_t u[8]; bf16x8 v; };

__device__ __forceinline__ bf16x8 cvt8_f32_bf16(const float* __restrict__ p){
  float4 v0 = *(const float4*)(const void*)p;
  float4 v1 = *(const float4*)(const void*)(p + 4);
  Frag8 f;
  f.u[0] = f2b(v0.x); f.u[1] = f2b(v0.y); f.u[2] = f2b(v0.z); f.u[3] = f2b(v0.w);
  f.u[4] = f2b(v1.x); f.u[5] = f2b(v1.y); f.u[6] = f2b(v1.z); f.u[7] = f2b(v1.w);
  return f.v;
}

// ---- phase 1: edge bucketing only ----
__global__ __launch_bounds__(256) void k_p1(const int* __restrict__ src,
                                            const int* __restrict__ dst,
                                            int* __restrict__ gBucket,   // stride 16 ints
                                            int2* __restrict__ ebuf){
  __shared__ int sMem[NBUCK*3];
  int* cntL  = sMem;
  int* baseL = cntL + NBUCK;
  int* ofsL  = baseL + NBUCK;
  int t = threadIdx.x;
  #pragma unroll
  for (int r = 0; r < 2; ++r){
    int i = t + r*256;
    cntL[i] = 0; ofsL[i] = 0;
  }
  __syncthreads();

  int base = blockIdx.x * 4096;
  int e0 = base + t*16;
  int s[16], d[16];
  int ne = 0;
  if (e0 + 16 <= NEDGES){
    #pragma unroll
    for (int q = 0; q < 4; ++q){
      int4 sv = *(const int4*)(src + e0 + q*4);
      int4 dv = *(const int4*)(dst + e0 + q*4);
      s[q*4+0]=sv.x; s[q*4+1]=sv.y; s[q*4+2]=sv.z; s[q*4+3]=sv.w;
      d[q*4+0]=dv.x; d[q*4+1]=dv.y; d[q*4+2]=dv.z; d[q*4+3]=dv.w;
    }
    ne = 16;
  } else {
    for (int e = e0; e < NEDGES && ne < 16; ++e, ++ne){
      s[ne] = src[e]; d[ne] = dst[e];
    }
  }
  for (int k = 0; k < ne; ++k) atomicAdd(&cntL[d[k] >> BSH], 1);
  __syncthreads();
  #pragma unroll
  for (int r = 0; r < 2; ++r){
    int i = t + r*256;
    int c = cntL[i];
    baseL[i] = c ? atomicAdd(&gBucket[i*16], c) : 0;
  }
  __syncthreads();
  for (int k = 0; k < ne; ++k){
    int b = d[k] >> BSH;
    int o = atomicAdd(&ofsL[b], 1);
    ebuf[(size_t)b*BCAP + baseL[b] + o] = make_int2(s[k], d[k]);
  }
}

// ---- phase 2: per-bucket placement into colx + cnt + pad ----
// pad rule: slots [c, ce) <- NNODES (zero row); ce = 15 for c<=15, else 31.
__global__ __launch_bounds__(256) void k_p2(const int2* __restrict__ ebuf,
                                            const int* __restrict__ gBucket,
                                            int* __restrict__ colx,
                                            int* __restrict__ cnt){
  __shared__ int slotcnt[256];
  int t = threadIdx.x;
  int b = blockIdx.x;
  slotcnt[t] = 0;
  __syncthreads();

  int nb = gBucket[b*16];
  int vbase = b << BSH;

  for (int e = t; e < nb; e += 256){
    int2 p = ebuf[(size_t)b*BCAP + e];
    int slot = atomicAdd(&slotcnt[p.y - vbase], 1);
    colx[p.y*DEGCAP + slot] = p.x;
  }
  __syncthreads();

  int v = vbase + t;
  if (v < NNODES){
    int c = slotcnt[t];
    cnt[v] = c;
    int ce = (c <= 15) ? 15 : 31;
    for (int s = c; s < ce; ++s) colx[(size_t)v*DEGCAP + s] = NNODES;
  }
}

// ---- GEMM layer 0: hs[m][n] = bf16( (sum_k x[m][k]*W0[k][n]) * rsqrt(cnt[m]+1) ) ----
// block 0 also zero-inits the hs padding row (index NNODES).
__global__ __launch_bounds__(256) void k_gemm0(const float* __restrict__ x,
                                               const float* __restrict__ W0,
                                               const int* __restrict__ cnt,
                                               ushort_t* __restrict__ hs){
  __shared__ __attribute__((aligned(16))) ushort_t sWT[128*136];
  if (blockIdx.x == 0 && threadIdx.x < 64)
    ((uint_t*)hs)[(size_t)NNODES*64 + threadIdx.x] = 0u;
  for (int idx = threadIdx.x; idx < 128*128; idx += 256){
    int c = idx >> 7, jj = idx & 127;
    sWT[jj*136 + c] = f2b(W0[idx]);
  }
  __syncthreads();

  int wave = threadIdx.x >> 6;
  int lane = threadIdx.x & 63;
  int quad = lane >> 4;
  int l16  = lane & 15;
  int row0 = blockIdx.x*64 + wave*16;

  int m  = row0 + l16;
  int mc = (m < NNODES) ? m : (NNODES - 1);

  const float* ap = x + (size_t)mc*128 + quad*8;
  bf16x8 af0 = cvt8_f32_bf16(ap);
  bf16x8 af1 = cvt8_f32_bf16(ap + 32);
  bf16x8 af2 = cvt8_f32_bf16(ap + 64);
  bf16x8 af3 = cvt8_f32_bf16(ap + 96);

  f32x4 acc[8];
  #pragma unroll
  for (int ct = 0; ct < 8; ++ct){
    const ushort_t* bp = sWT + (ct*16 + l16)*136 + quad*8;
    bf16x8 b0 = *(const bf16x8*)(const void*)(bp);
    bf16x8 b1 = *(const bf16x8*)(const void*)(bp + 32);
    bf16x8 b2 = *(const bf16x8*)(const void*)(bp + 64);
    bf16x8 b3 = *(const bf16x8*)(const void*)(bp + 96);
    f32x4 a_ = {0.f, 0.f, 0.f, 0.f};
    a_ = mfma_bf16(af0, b0, a_);
    a_ = mfma_bf16(af1, b1, a_);
    a_ = mfma_bf16(af2, b2, a_);
    a_ = mfma_bf16(af3, b3, a_);
    acc[ct] = a_;
  }

  int rbase = row0 + quad*4;
  float dv[4];
  #pragma unroll
  for (int rg = 0; rg < 4; ++rg){
    int rr = rbase + rg;
    int cc = cnt[(rr < NNODES) ? rr : (NNODES - 1)];
    dv[rg] = rsqrtf((float)(cc + 1));
  }
  #pragma unroll
  for (int ct = 0; ct < 8; ++ct){
    int colc = ct*16 + l16;
    #pragma unroll
    for (int rg = 0; rg < 4; ++rg){
      int rr = rbase + rg;
      if (rr < NNODES) hs[(size_t)rr*128 + colc] = f2b(acc[ct][rg] * dv[rg]);
    }
  }
}

// ---- GEMM layers 1,2 with BN-fold computed in-block (k_fold eliminated):
//   a[c]=gamma[c]*rsqrt(var+eps); cc[c]=beta[c]-mu*a[c]
//   sWT[j][c]=bf16(a[c]*Wn[c][j]); Kv[j]=sum_c cc[c]*Wn[c][j]  (LDS atomics)
//   hs[m][n] = bf16( (sum_k A[m][k]*sWT[n][k] + Kv[n]) * rsqrt(cnt[m]+1) )
__global__ __launch_bounds__(256) void k_gemmf(const ushort_t* __restrict__ A,
                                               const float* __restrict__ Wn,
                                               const float* __restrict__ chansum,
                                               const float* __restrict__ chansumsq,
                                               const float* __restrict__ gamma,
                                               const float* __restrict__ beta,
                                               const int* __restrict__ cnt,
                                               ushort_t* __restrict__ hs){
  __shared__ __attribute__((aligned(16))) ushort_t sWT[128*136];
  __shared__ float aL[128];
  __shared__ float cL[128];
  __shared__ float KvL[128];

  int t = threadIdx.x;
  if (t < 128){
    const float invN = 1.0f / (float)NNODES;
    float mu  = chansum[t] * invN;
    float var = chansumsq[t] * invN - mu*mu;
    float a = gamma[t] * rsqrtf(var + EPSBN);
    aL[t] = a;
    cL[t] = beta[t] - mu*a;
    KvL[t] = 0.f;
  }
  __syncthreads();
  for (int idx = t; idx < 128*128; idx += 256){
    int c = idx >> 7, jj = idx & 127;
    float wv = Wn[idx];
    sWT[jj*136 + c] = f2b(aL[c] * wv);
    atomicAdd(&KvL[jj], cL[c] * wv);
  }
  __syncthreads();

  int wave = t >> 6;
  int lane = t & 63;
  int quad = lane >> 4;
  int l16  = lane & 15;
  int row0 = blockIdx.x*64 + wave*16;

  int m  = row0 + l16;
  int mc = (m < NNODES) ? m : (NNODES - 1);

  const ushort_t* ap = A + (size_t)mc*128 + quad*8;
  bf16x8 af0 = *(const bf16x8*)(const void*)(ap);
  bf16x8 af1 = *(const bf16x8*)(const void*)(ap + 32);
  bf16x8 af2 = *(const bf16x8*)(const void*)(ap + 64);
  bf16x8 af3 = *(const bf16x8*)(const void*)(ap + 96);

  f32x4 acc[8];
  #pragma unroll
  for (int ct = 0; ct < 8; ++ct){
    const ushort_t* bp = sWT + (ct*16 + l16)*136 + quad*8;
    bf16x8 b0 = *(const bf16x8*)(const void*)(bp);
    bf16x8 b1 = *(const bf16x8*)(const void*)(bp + 32);
    bf16x8 b2 = *(const bf16x8*)(const void*)(bp + 64);
    bf16x8 b3 = *(const bf16x8*)(const void*)(bp + 96);
    f32x4 a_ = {0.f, 0.f, 0.f, 0.f};
    a_ = mfma_bf16(af0, b0, a_);
    a_ = mfma_bf16(af1, b1, a_);
    a_ = mfma_bf16(af2, b2, a_);
    a_ = mfma_bf16(af3, b3, a_);
    acc[ct] = a_;
  }

  int rbase = row0 + quad*4;
  float dv[4];
  #pragma unroll
  for (int rg = 0; rg < 4; ++rg){
    int rr = rbase + rg;
    int cc = cnt[(rr < NNODES) ? rr : (NNODES - 1)];
    dv[rg] = rsqrtf((float)(cc + 1));
  }
  #pragma unroll
  for (int ct = 0; ct < 8; ++ct){
    int colc = ct*16 + l16;
    float kv = KvL[colc];
    #pragma unroll
    for (int rg = 0; rg < 4; ++rg){
      int rr = rbase + rg;
      if (rr < NNODES){
        float val = (acc[ct][rg] + kv) * dv[rg];
        hs[(size_t)rr*128 + colc] = f2b(val);
      }
    }
  }
}

// ---- aggregation: paired-row dwordx2 gathers (2 rows per vmem instruction),
//      2-node software pipeline (R4/R6 structure — best measured: 73.7 us) ----
#define AGG_BLOCKS 1024
#define AGG_WAVES (AGG_BLOCKS*4)   // 4096 waves = 16 waves/CU (proven sweet spot)
#define AGG_CHUNK ((NNODES + AGG_WAVES - 1) / AGG_WAVES)

#define FENCE8(A) asm volatile("" :: \
  "v"(A[0]),"v"(A[1]),"v"(A[2]),"v"(A[3]),"v"(A[4]),"v"(A[5]),"v"(A[6]),"v"(A[7]))

// round-0: pairs (self, c0),(c1,c2),...,(c13,c14)  -> self + slots 0..14
#define ISSUE_R0(dst, cr, vv) do { \
  _Pragma("unroll") \
  for (int k_ = 0; k_ < 8; ++k_){ \
    int uA_ = (k_ == 0) ? (vv) : __builtin_amdgcn_readlane((cr), 2*k_ - 1); \
    int uB_ = __builtin_amdgcn_readlane((cr), 2*k_); \
    int u_  = sel ? uB_ : uA_; \
    (dst)[k_] = H2[(uint_t)u_*32u + m]; \
  } \
} while(0)

// round-1: pairs over slots 15..30
#define ISSUE_R1(dst, cr) do { \
  _Pragma("unroll") \
  for (int k_ = 0; k_ < 8; ++k_){ \
    int uA_ = __builtin_amdgcn_readlane((cr), 15 + 2*k_); \
    int uB_ = __builtin_amdgcn_readlane((cr), 16 + 2*k_); \
    int u_  = sel ? uB_ : uA_; \
    (dst)[k_] = H2[(uint_t)u_*32u + m]; \
  } \
} while(0)

#define CONSUME8(A) do { \
  FENCE8(A); \
  _Pragma("unroll") \
  for (int k_ = 0; k_ < 8; ++k_){ \
    a0 += lo16((A)[k_].x); a1 += hi16((A)[k_].x); \
    a2 += lo16((A)[k_].y); a3 += hi16((A)[k_].y); \
  } \
} while(0)

template<bool WR>
__global__ __launch_bounds__(256, 4) void k_agg(const ushort_t* __restrict__ hs,
                                                const int* __restrict__ cnt,
                                                const int* __restrict__ colx,
                                                const float* __restrict__ bias,
                                                const int* __restrict__ batch,
                                                ushort_t* __restrict__ rout,
                                                float* __restrict__ poolS,
                                                float* __restrict__ chansum,
                                                float* __restrict__ chansumsq){
  __shared__ float bsum[128];
  __shared__ float bsq[128];
  if (threadIdx.x < 128){ bsum[threadIdx.x] = 0.f; bsq[threadIdx.x] = 0.f; }
  __syncthreads();

  int wave = __builtin_amdgcn_readfirstlane((blockIdx.x << 2) + (threadIdx.x >> 6));
  int lane = threadIdx.x & 63;
  int m    = lane & 31;          // uintx2 index within a row (channels 4m..4m+3)
  int sel  = lane >> 5;          // 0: row-A series, 1: row-B series
  int n0 = wave * AGG_CHUNK;
  int n1 = (n0 + AGG_CHUNK < NNODES) ? (n0 + AGG_CHUNK) : NNODES;

  const uintx2* H2 = (const uintx2*)hs;
  uintx2* R2 = (uintx2*)rout;

  float bbv[4];
  #pragma unroll
  for (int i = 0; i < 4; ++i) bbv[i] = bias[4*m + i];
  int chbase = 4*m + 2*sel;

  float ss0 = 0.f, ss1 = 0.f, sq0 = 0.f, sq1 = 0.f;
  float p0 = 0.f, p1 = 0.f;
  int curg = -1;

  if (n0 < n1){
    // ---- prologue: metadata for v0,v0+1; rounds 0(+1) for v0 ----
    int cr0 = colx[(size_t)n0*DEGCAP + lane];
    int cv0 = cnt[n0];
    int cr1 = 0, cv1 = 0;
    if (n0 + 1 < n1){
      cr1 = colx[(size_t)(n0+1)*DEGCAP + lane];
      cv1 = cnt[n0+1];
    }
    uintx2 e0[8], e1[8];
    ISSUE_R0(e0, cr0, n0);
    if (cv0 > 15) ISSUE_R1(e1, cr0);
    else { _Pragma("unroll") for (int k_ = 0; k_ < 8; ++k_) e1[k_] = (uintx2){0u,0u}; }

    for (int v = n0; v < n1; ++v){
      // 1) metadata for v+2
      int v2 = v + 2;
      int cr2 = 0, cv2 = 0;
      if (v2 < n1){
        cr2 = colx[(size_t)v2*DEGCAP + lane];
        cv2 = cnt[v2];
      }

      // 2) issue next node's rounds 0 (+1) — consumed next iteration
      uintx2 f0[8], f1[8];
      bool hasn = (v + 1 < n1);
      if (hasn){
        ISSUE_R0(f0, cr1, v + 1);
        if (cv1 > 15) ISSUE_R1(f1, cr1);
        else { _Pragma("unroll") for (int k_ = 0; k_ < 8; ++k_) f1[k_] = (uintx2){0u,0u}; }
      } else {
        _Pragma("unroll") for (int k_ = 0; k_ < 8; ++k_){ f0[k_] = (uintx2){0u,0u}; f1[k_] = (uintx2){0u,0u}; }
      }

      // group bookkeeping (overlaps with in-flight loads)
      int g = batch[v];
      if (g != curg){
        if (curg >= 0){
          atomicAdd(&poolS[curg*128 + chbase],     p0);
          atomicAdd(&poolS[curg*128 + chbase + 1], p1);
        }
        p0 = 0.f; p1 = 0.f; curg = g;
      }

      float a0 = 0.f, a1 = 0.f, a2 = 0.f, a3 = 0.f;

      // 3) consume current node's in-flight rounds (issued one node ago)
      CONSUME8(e0);
      if (cv0 > 15) CONSUME8(e1);
      if (cv0 > 31){
        // rare (P ~ 1e-4): sequential paired tail over slots 31..cv0-1
        for (int j = 31; j < cv0; j += 2){
          int uA = __builtin_amdgcn_readlane(cr0, j);
          int uB = (j + 1 < cv0) ? __builtin_amdgcn_readlane(cr0, j + 1) : NNODES;
          int u  = sel ? uB : uA;
          uintx2 dd = H2[(uint_t)u*32u + m];
          a0 += lo16(dd.x); a1 += hi16(dd.x);
          a2 += lo16(dd.y); a3 += hi16(dd.y);
        }
      }

      // 4) combine half-wave series: s = lowerA + upperB per channel
      float s0 = a0 + __shfl_xor(a0, 32, 64);
      float s1 = a1 + __shfl_xor(a1, 32, 64);
      float s2 = a2 + __shfl_xor(a2, 32, 64);
      float s3 = a3 + __shfl_xor(a3, 32, 64);

      // 5) epilogue
      float dvv = rsqrtf((float)(cv0 + 1));
      float r0 = fmaxf(s0*dvv + bbv[0], 0.f);
      float r1 = fmaxf(s1*dvv + bbv[1], 0.f);
      float r2 = fmaxf(s2*dvv + bbv[2], 0.f);
      float r3 = fmaxf(s3*dvv + bbv[3], 0.f);
      if constexpr (WR){
        if (lane < 32){
          uintx2 wv;
          wv.x = pkbf(r0, r1);
          wv.y = pkbf(r2, r3);
          R2[(uint_t)v*32u + m] = wv;
        }
      }
      float cA = sel ? r2 : r0;
      float cB = sel ? r3 : r1;
      ss0 += cA; ss1 += cB;
      sq0 += cA*cA; sq1 += cB*cB;
      p0 += cA; p1 += cB;

      // 6) rotate pipeline state
      cr0 = cr1; cv0 = cv1;
      cr1 = cr2; cv1 = cv2;
      #pragma unroll
      for (int k_ = 0; k_ < 8; ++k_){ e0[k_] = f0[k_]; e1[k_] = f1[k_]; }
    }
  }

  if (curg >= 0){
    atomicAdd(&poolS[curg*128 + chbase],     p0);
    atomicAdd(&poolS[curg*128 + chbase + 1], p1);
  }
  atomicAdd(&bsum[chbase],     ss0);
  atomicAdd(&bsum[chbase + 1], ss1);
  atomicAdd(&bsq[chbase],      sq0);
  atomicAdd(&bsq[chbase + 1],  sq1);
  __syncthreads();
  if (threadIdx.x < 128){
    atomicAdd(&chansum[threadIdx.x],   bsum[threadIdx.x]);
    atomicAdd(&chansumsq[threadIdx.x], bsq[threadIdx.x]);
  }
}

// ---- final: per-graph output for all 3 layers; BN affine computed inline;
//      per-graph node count via binary search on sorted batch ----
__global__ void k_final(const float* __restrict__ poolS,
                        const int* __restrict__ batch,
                        const float* __restrict__ chanstats,   // 3 layers x [sum(128), sumsq(128)]
                        const float* __restrict__ g0, const float* __restrict__ t0,
                        const float* __restrict__ g1, const float* __restrict__ t1,
                        const float* __restrict__ g2, const float* __restrict__ t2,
                        float* __restrict__ out){
  __shared__ int s_n[2];
  int g = blockIdx.x, c = threadIdx.x;
  if (c < 2){
    int target = g + c;
    int lo = 0, hi = NNODES;
    while (lo < hi){
      int mid = (lo + hi) >> 1;
      if (batch[mid] < target) lo = mid + 1; else hi = mid;
    }
    s_n[c] = lo;
  }
  __syncthreads();
  float n = (float)(s_n[1] - s_n[0]);

  const float* gam[3] = {g0, g1, g2};
  const float* bet[3] = {t0, t1, t2};
  const float invN = 1.0f / (float)NNODES;
  #pragma unroll
  for (int i = 0; i < 3; ++i){
    float mu  = chanstats[i*256 + c] * invN;
    float var = chanstats[i*256 + 128 + c] * invN - mu*mu;
    float a = gam[i][c] * rsqrtf(var + EPSBN);
    float cc = bet[i][c] - mu*a;
    float v = a * poolS[((size_t)i*NGRAPH + g)*128 + c] + n * cc;
    out[(size_t)g*384 + i*128 + c] = v;
  }
}

extern "C" void kernel_launch(void* const* d_in, const int* in_sizes, int n_in,
                              void* d_out, int out_size, void* d_ws, size_t ws_size,
                              hipStream_t stream){
  (void)in_sizes; (void)n_in; (void)out_size; (void)ws_size;

  const float* x     = (const float*)d_in[0];
  const int*   ei    = (const int*)d_in[1];
  const int*   batch = (const int*)d_in[2];
  const float* Wp[3] = {(const float*)d_in[3], (const float*)d_in[7],  (const float*)d_in[11]};
  const float* bp[3] = {(const float*)d_in[4], (const float*)d_in[8],  (const float*)d_in[12]};
  const float* gp[3] = {(const float*)d_in[5], (const float*)d_in[9],  (const float*)d_in[13]};
  const float* tp[3] = {(const float*)d_in[6], (const float*)d_in[10], (const float*)d_in[14]};
  const int* srcp = ei;
  const int* dstp = ei + NEDGES;

  char* w = (char*)d_ws;
  size_t off = 0;
  auto take = [&](size_t bytes) -> char* {
    char* p = w + off;
    off += (bytes + 511) & ~(size_t)511;
    return p;
  };
  int*      cnt       = (int*)take((size_t)NNODES*4);
  int*      colx      = (int*)take((size_t)NNODES*DEGCAP*4);
  ushort_t* hs        = (ushort_t*)take((size_t)(NNODES+1)*128*2);  // +1 zero row for gather padding
  ushort_t* rbuf      = (ushort_t*)take((size_t)NNODES*128*2);   // also aliased as ebuf pre-agg0
  // single contiguous zero region: gBucket | chanstats | poolS
  const size_t ZB_GB = (size_t)NBUCK*16*4;            // 32768
  const size_t ZB_CS = 3*256*4;                       // 3072
  const size_t ZB_PS = (size_t)3*NGRAPH*128*4;        // 786432
  char* zbase = take(ZB_GB + ZB_CS + ZB_PS);
  int*   gBucket   = (int*)zbase;
  float* chanstats = (float*)(zbase + ZB_GB);
  float* poolS     = (float*)(zbase + ZB_GB + ZB_CS);

  // ebuf aliases rbuf: ebuf consumed by k_p2 before agg0 first writes rbuf.
  int2* ebuf = (int2*)rbuf;   // needs NBUCK*BCAP*8 = 19.9 MB <= 25.6 MB

  hipMemsetAsync(zbase, 0, ZB_GB + ZB_CS + ZB_PS, stream);

  // phase 1: bucket edges
  k_p1<<<P1_BLOCKS, 256, 0, stream>>>(srcp, dstp, gBucket, ebuf);
  // phase 2: place colx, write cnt, pad colx (to 15 or 31)
  k_p2<<<NBUCK, 256, 0, stream>>>(ebuf, gBucket, colx, cnt);
  // GEMM0 with normalization folded into epilogue; also zero-inits hs pad row
  k_gemm0<<<GEMM_BLOCKS, 256, 0, stream>>>(x, Wp[0], cnt, hs);

  // layer 0
  k_agg<true><<<AGG_BLOCKS, 256, 0, stream>>>(hs, cnt, colx, bp[0], batch, rbuf,
                                              poolS, chanstats, chanstats + 128);
  // layer 1 (BN fold of layer-0 stats computed in-block)
  k_gemmf<<<GEMM_BLOCKS, 256, 0, stream>>>(rbuf, Wp[1], chanstats, chanstats + 128,
                                           gp[0], tp[0], cnt, hs);
  k_agg<true><<<AGG_BLOCKS, 256, 0, stream>>>(hs, cnt, colx, bp[1], batch, rbuf,
                                              poolS + (size_t)NGRAPH*128,
                                              chanstats + 256, chanstats + 256 + 128);
  // layer 2
  k_gemmf<<<GEMM_BLOCKS, 256, 0, stream>>>(rbuf, Wp[2], chanstats + 256, chanstats + 256 + 128,
                                           gp[1], tp[1], cnt, hs);
  k_agg<false><<<AGG_BLOCKS, 256, 0, stream>>>(hs, cnt, colx, bp[2], batch, rbuf,
                                               poolS + (size_t)2*NGRAPH*128,
                                               chanstats + 512, chanstats + 512 + 128);

  k_final<<<NGRAPH, 128, 0, stream>>>(poolS, batch, chanstats,
                                      gp[0], tp[0], gp[1], tp[1], gp[2], tp[2],
                                      (float*)d_out);
}

// Round 11
// 436.837 us; speedup vs baseline: 1.6280x; 1.6280x over previous
//
#include <hip/hip_runtime.h>

#define NNODES 100000
#define NEDGES 1600000
#define NGRAPH 512
#define EPSBN 1e-5f
#define DEGCAP 64    // max in-degree; Binomial tail beyond 64 ~1e-20
#define NBUCK 512    // dst buckets of 256 nodes (391 used)
#define BSH 8
#define BCAP 4864    // per-bucket capacity: mean 4096, sd 64, +12 sigma margin
#define P1_BLOCKS ((NEDGES + 4095)/4096)   // 391
#define GEMM_BLOCKS ((NNODES + 63)/64)     // 1563

typedef unsigned short ushort_t;
typedef unsigned int uint_t;

typedef __attribute__((ext_vector_type(8))) __bf16 bf16x8;
typedef __attribute__((ext_vector_type(4))) float f32x4;
typedef __attribute__((ext_vector_type(2))) uint_t uintx2;

__device__ __forceinline__ float b2f(ushort_t u){ return __uint_as_float(((uint_t)u)<<16); }
// native bf16 convert (RNE) — compiler emits v_cvt_pk_bf16_f32
__device__ __forceinline__ ushort_t f2b(float f){
  union { __bf16 h; ushort_t u; } c;
  c.h = (__bf16)f;
  return c.u;
}
__device__ __forceinline__ uint_t pkbf(float a, float b){
  union { __bf16 h[2]; uint_t u; } c;
  c.h[0] = (__bf16)a; c.h[1] = (__bf16)b;
  return c.u;
}
__device__ __forceinline__ float lo16(uint_t d){ return b2f((ushort_t)(d & 0xffffu)); }
__device__ __forceinline__ float hi16(uint_t d){ return b2f((ushort_t)(d >> 16)); }

__device__ __forceinline__ f32x4 mfma_bf16(bf16x8 a, bf16x8 b, f32x4 c){
  return __builtin_amdgcn_mfma_f32_16x16x32_bf16(a, b, c, 0, 0, 0);
}

union Frag8 { ushort_t u[8]; bf16x8 v; };

__device__ __forceinline__ bf16x8 cvt8_f32_bf16(const float* __restrict__ p){
  float4 v0 = *(const float4*)(const void*)p;
  float4 v1 = *(const float4*)(const void*)(p + 4);
  Frag8 f;
  f.u[0] = f2b(v0.x); f.u[1] = f2b(v0.y); f.u[2] = f2b(v0.z); f.u[3] = f2b(v0.w);
  f.u[4] = f2b(v1.x); f.u[5] = f2b(v1.y); f.u[6] = f2b(v1.z); f.u[7] = f2b(v1.w);
  return f.v;
}

// ---- phase 1: edge bucketing only ----
__global__ __launch_bounds__(256) void k_p1(const int* __restrict__ src,
                                            const int* __restrict__ dst,
                                            int* __restrict__ gBucket,   // stride 16 ints
                                            int2* __restrict__ ebuf){
  __shared__ int sMem[NBUCK*3];
  int* cntL  = sMem;
  int* baseL = cntL + NBUCK;
  int* ofsL  = baseL + NBUCK;
  int t = threadIdx.x;
  #pragma unroll
  for (int r = 0; r < 2; ++r){
    int i = t + r*256;
    cntL[i] = 0; ofsL[i] = 0;
  }
  __syncthreads();

  int base = blockIdx.x * 4096;
  int e0 = base + t*16;
  int s[16], d[16];
  int ne = 0;
  if (e0 + 16 <= NEDGES){
    #pragma unroll
    for (int q = 0; q < 4; ++q){
      int4 sv = *(const int4*)(src + e0 + q*4);
      int4 dv = *(const int4*)(dst + e0 + q*4);
      s[q*4+0]=sv.x; s[q*4+1]=sv.y; s[q*4+2]=sv.z; s[q*4+3]=sv.w;
      d[q*4+0]=dv.x; d[q*4+1]=dv.y; d[q*4+2]=dv.z; d[q*4+3]=dv.w;
    }
    ne = 16;
  } else {
    for (int e = e0; e < NEDGES && ne < 16; ++e, ++ne){
      s[ne] = src[e]; d[ne] = dst[e];
    }
  }
  for (int k = 0; k < ne; ++k) atomicAdd(&cntL[d[k] >> BSH], 1);
  __syncthreads();
  #pragma unroll
  for (int r = 0; r < 2; ++r){
    int i = t + r*256;
    int c = cntL[i];
    baseL[i] = c ? atomicAdd(&gBucket[i*16], c) : 0;
  }
  __syncthreads();
  for (int k = 0; k < ne; ++k){
    int b = d[k] >> BSH;
    int o = atomicAdd(&ofsL[b], 1);
    ebuf[(size_t)b*BCAP + baseL[b] + o] = make_int2(s[k], d[k]);
  }
}

// ---- phase 2: per-bucket placement into colx + cnt + pad ----
// pad rule: slots [c, ce) <- NNODES (zero row); ce = 15 for c<=15, else 31.
__global__ __launch_bounds__(256) void k_p2(const int2* __restrict__ ebuf,
                                            const int* __restrict__ gBucket,
                                            int* __restrict__ colx,
                                            int* __restrict__ cnt){
  __shared__ int slotcnt[256];
  int t = threadIdx.x;
  int b = blockIdx.x;
  slotcnt[t] = 0;
  __syncthreads();

  int nb = gBucket[b*16];
  int vbase = b << BSH;

  for (int e = t; e < nb; e += 256){
    int2 p = ebuf[(size_t)b*BCAP + e];
    int slot = atomicAdd(&slotcnt[p.y - vbase], 1);
    colx[p.y*DEGCAP + slot] = p.x;
  }
  __syncthreads();

  int v = vbase + t;
  if (v < NNODES){
    int c = slotcnt[t];
    cnt[v] = c;
    int ce = (c <= 15) ? 15 : 31;
    for (int s = c; s < ce; ++s) colx[(size_t)v*DEGCAP + s] = NNODES;
  }
}

// ---- GEMM layer 0: hs[m][n] = bf16( (sum_k x[m][k]*W0[k][n]) * rsqrt(cnt[m]+1) ) ----
// block 0 also zero-inits the hs padding row (index NNODES).
__global__ __launch_bounds__(256) void k_gemm0(const float* __restrict__ x,
                                               const float* __restrict__ W0,
                                               const int* __restrict__ cnt,
                                               ushort_t* __restrict__ hs){
  __shared__ __attribute__((aligned(16))) ushort_t sWT[128*136];
  if (blockIdx.x == 0 && threadIdx.x < 64)
    ((uint_t*)hs)[(size_t)NNODES*64 + threadIdx.x] = 0u;
  for (int idx = threadIdx.x; idx < 128*128; idx += 256){
    int c = idx >> 7, jj = idx & 127;
    sWT[jj*136 + c] = f2b(W0[idx]);
  }
  __syncthreads();

  int wave = threadIdx.x >> 6;
  int lane = threadIdx.x & 63;
  int quad = lane >> 4;
  int l16  = lane & 15;
  int row0 = blockIdx.x*64 + wave*16;

  int m  = row0 + l16;
  int mc = (m < NNODES) ? m : (NNODES - 1);

  const float* ap = x + (size_t)mc*128 + quad*8;
  bf16x8 af0 = cvt8_f32_bf16(ap);
  bf16x8 af1 = cvt8_f32_bf16(ap + 32);
  bf16x8 af2 = cvt8_f32_bf16(ap + 64);
  bf16x8 af3 = cvt8_f32_bf16(ap + 96);

  f32x4 acc[8];
  #pragma unroll
  for (int ct = 0; ct < 8; ++ct){
    const ushort_t* bp = sWT + (ct*16 + l16)*136 + quad*8;
    bf16x8 b0 = *(const bf16x8*)(const void*)(bp);
    bf16x8 b1 = *(const bf16x8*)(const void*)(bp + 32);
    bf16x8 b2 = *(const bf16x8*)(const void*)(bp + 64);
    bf16x8 b3 = *(const bf16x8*)(const void*)(bp + 96);
    f32x4 a_ = {0.f, 0.f, 0.f, 0.f};
    a_ = mfma_bf16(af0, b0, a_);
    a_ = mfma_bf16(af1, b1, a_);
    a_ = mfma_bf16(af2, b2, a_);
    a_ = mfma_bf16(af3, b3, a_);
    acc[ct] = a_;
  }

  int rbase = row0 + quad*4;
  float dv[4];
  #pragma unroll
  for (int rg = 0; rg < 4; ++rg){
    int rr = rbase + rg;
    int cc = cnt[(rr < NNODES) ? rr : (NNODES - 1)];
    dv[rg] = rsqrtf((float)(cc + 1));
  }
  #pragma unroll
  for (int ct = 0; ct < 8; ++ct){
    int colc = ct*16 + l16;
    #pragma unroll
    for (int rg = 0; rg < 4; ++rg){
      int rr = rbase + rg;
      if (rr < NNODES) hs[(size_t)rr*128 + colc] = f2b(acc[ct][rg] * dv[rg]);
    }
  }
}

// ---- fold: BN-scaled weights WT[j][c]=bf16(a[c]*Wn[c][j]), Kv[j]=sum_c cc[c]*Wn[c][j] ----
// (proven R6 structure; avec/cvec dropped — k_final recomputes BN affine inline)
__global__ void k_fold(const float* __restrict__ Wn,
                       const float* __restrict__ chansum, const float* __restrict__ chansumsq,
                       const float* __restrict__ gamma, const float* __restrict__ beta,
                       ushort_t* __restrict__ WT, float* __restrict__ Kv){
  __shared__ float red[128];
  int j = blockIdx.x, c = threadIdx.x;
  const float invN = 1.0f / (float)NNODES;
  float mu  = chansum[c] * invN;
  float var = chansumsq[c] * invN - mu*mu;
  float a = gamma[c] * rsqrtf(var + EPSBN);
  float cc = beta[c] - mu*a;
  float wv = Wn[c*128 + j];
  WT[j*136 + c] = f2b(a * wv);
  red[c] = cc * wv;
  __syncthreads();
  for (int off = 64; off > 0; off >>= 1){
    if (c < off) red[c] += red[c + off];
    __syncthreads();
  }
  if (c == 0) Kv[j] = red[0];
}

// ---- GEMM layers 1,2: hs[m][n] = bf16( (sum_k A[m][k]*WT[n][k] + K[n]) * rsqrt(cnt[m]+1) ) ----
__global__ __launch_bounds__(256) void k_gemm(const ushort_t* __restrict__ A,
                                              const ushort_t* __restrict__ WT,
                                              const float* __restrict__ Kv,
                                              const int* __restrict__ cnt,
                                              ushort_t* __restrict__ hs){
  __shared__ __attribute__((aligned(16))) ushort_t sWT[128*136];
  {
    const uint4* sp = (const uint4*)WT;
    uint4* dp = (uint4*)sWT;
    for (int i = threadIdx.x; i < (128*136*2)/16; i += 256) dp[i] = sp[i];
  }
  __syncthreads();

  int wave = threadIdx.x >> 6;
  int lane = threadIdx.x & 63;
  int quad = lane >> 4;
  int l16  = lane & 15;
  int row0 = blockIdx.x*64 + wave*16;

  int m  = row0 + l16;
  int mc = (m < NNODES) ? m : (NNODES - 1);

  const ushort_t* ap = A + (size_t)mc*128 + quad*8;
  bf16x8 af0 = *(const bf16x8*)(const void*)(ap);
  bf16x8 af1 = *(const bf16x8*)(const void*)(ap + 32);
  bf16x8 af2 = *(const bf16x8*)(const void*)(ap + 64);
  bf16x8 af3 = *(const bf16x8*)(const void*)(ap + 96);

  f32x4 acc[8];
  #pragma unroll
  for (int ct = 0; ct < 8; ++ct){
    const ushort_t* bp = sWT + (ct*16 + l16)*136 + quad*8;
    bf16x8 b0 = *(const bf16x8*)(const void*)(bp);
    bf16x8 b1 = *(const bf16x8*)(const void*)(bp + 32);
    bf16x8 b2 = *(const bf16x8*)(const void*)(bp + 64);
    bf16x8 b3 = *(const bf16x8*)(const void*)(bp + 96);
    f32x4 a_ = {0.f, 0.f, 0.f, 0.f};
    a_ = mfma_bf16(af0, b0, a_);
    a_ = mfma_bf16(af1, b1, a_);
    a_ = mfma_bf16(af2, b2, a_);
    a_ = mfma_bf16(af3, b3, a_);
    acc[ct] = a_;
  }

  int rbase = row0 + quad*4;
  float dv[4];
  #pragma unroll
  for (int rg = 0; rg < 4; ++rg){
    int rr = rbase + rg;
    int cc = cnt[(rr < NNODES) ? rr : (NNODES - 1)];
    dv[rg] = rsqrtf((float)(cc + 1));
  }
  #pragma unroll
  for (int ct = 0; ct < 8; ++ct){
    int colc = ct*16 + l16;
    float kv = Kv[colc];
    #pragma unroll
    for (int rg = 0; rg < 4; ++rg){
      int rr = rbase + rg;
      if (rr < NNODES){
        float val = (acc[ct][rg] + kv) * dv[rg];
        hs[(size_t)rr*128 + colc] = f2b(val);
      }
    }
  }
}

// ---- aggregation: paired-row dwordx2 gathers (2 rows per vmem instruction),
//      2-node software pipeline (R4/R6 structure — best measured: 73.7 us) ----
#define AGG_BLOCKS 1024
#define AGG_WAVES (AGG_BLOCKS*4)   // 4096 waves = 16 waves/CU (proven sweet spot)
#define AGG_CHUNK ((NNODES + AGG_WAVES - 1) / AGG_WAVES)

#define FENCE8(A) asm volatile("" :: \
  "v"(A[0]),"v"(A[1]),"v"(A[2]),"v"(A[3]),"v"(A[4]),"v"(A[5]),"v"(A[6]),"v"(A[7]))

// round-0: pairs (self, c0),(c1,c2),...,(c13,c14)  -> self + slots 0..14
#define ISSUE_R0(dst, cr, vv) do { \
  _Pragma("unroll") \
  for (int k_ = 0; k_ < 8; ++k_){ \
    int uA_ = (k_ == 0) ? (vv) : __builtin_amdgcn_readlane((cr), 2*k_ - 1); \
    int uB_ = __builtin_amdgcn_readlane((cr), 2*k_); \
    int u_  = sel ? uB_ : uA_; \
    (dst)[k_] = H2[(uint_t)u_*32u + m]; \
  } \
} while(0)

// round-1: pairs over slots 15..30
#define ISSUE_R1(dst, cr) do { \
  _Pragma("unroll") \
  for (int k_ = 0; k_ < 8; ++k_){ \
    int uA_ = __builtin_amdgcn_readlane((cr), 15 + 2*k_); \
    int uB_ = __builtin_amdgcn_readlane((cr), 16 + 2*k_); \
    int u_  = sel ? uB_ : uA_; \
    (dst)[k_] = H2[(uint_t)u_*32u + m]; \
  } \
} while(0)

#define CONSUME8(A) do { \
  FENCE8(A); \
  _Pragma("unroll") \
  for (int k_ = 0; k_ < 8; ++k_){ \
    a0 += lo16((A)[k_].x); a1 += hi16((A)[k_].x); \
    a2 += lo16((A)[k_].y); a3 += hi16((A)[k_].y); \
  } \
} while(0)

template<bool WR>
__global__ __launch_bounds__(256, 4) void k_agg(const ushort_t* __restrict__ hs,
                                                const int* __restrict__ cnt,
                                                const int* __restrict__ colx,
                                                const float* __restrict__ bias,
                                                const int* __restrict__ batch,
                                                ushort_t* __restrict__ rout,
                                                float* __restrict__ poolS,
                                                float* __restrict__ chansum,
                                                float* __restrict__ chansumsq){
  __shared__ float bsum[128];
  __shared__ float bsq[128];
  if (threadIdx.x < 128){ bsum[threadIdx.x] = 0.f; bsq[threadIdx.x] = 0.f; }
  __syncthreads();

  int wave = __builtin_amdgcn_readfirstlane((blockIdx.x << 2) + (threadIdx.x >> 6));
  int lane = threadIdx.x & 63;
  int m    = lane & 31;          // uintx2 index within a row (channels 4m..4m+3)
  int sel  = lane >> 5;          // 0: row-A series, 1: row-B series
  int n0 = wave * AGG_CHUNK;
  int n1 = (n0 + AGG_CHUNK < NNODES) ? (n0 + AGG_CHUNK) : NNODES;

  const uintx2* H2 = (const uintx2*)hs;
  uintx2* R2 = (uintx2*)rout;

  float bbv[4];
  #pragma unroll
  for (int i = 0; i < 4; ++i) bbv[i] = bias[4*m + i];
  int chbase = 4*m + 2*sel;

  float ss0 = 0.f, ss1 = 0.f, sq0 = 0.f, sq1 = 0.f;
  float p0 = 0.f, p1 = 0.f;
  int curg = -1;

  if (n0 < n1){
    // ---- prologue: metadata for v0,v0+1; rounds 0(+1) for v0 ----
    int cr0 = colx[(size_t)n0*DEGCAP + lane];
    int cv0 = cnt[n0];
    int cr1 = 0, cv1 = 0;
    if (n0 + 1 < n1){
      cr1 = colx[(size_t)(n0+1)*DEGCAP + lane];
      cv1 = cnt[n0+1];
    }
    uintx2 e0[8], e1[8];
    ISSUE_R0(e0, cr0, n0);
    if (cv0 > 15) ISSUE_R1(e1, cr0);
    else { _Pragma("unroll") for (int k_ = 0; k_ < 8; ++k_) e1[k_] = (uintx2){0u,0u}; }

    for (int v = n0; v < n1; ++v){
      // 1) metadata for v+2
      int v2 = v + 2;
      int cr2 = 0, cv2 = 0;
      if (v2 < n1){
        cr2 = colx[(size_t)v2*DEGCAP + lane];
        cv2 = cnt[v2];
      }

      // 2) issue next node's rounds 0 (+1) — consumed next iteration
      uintx2 f0[8], f1[8];
      bool hasn = (v + 1 < n1);
      if (hasn){
        ISSUE_R0(f0, cr1, v + 1);
        if (cv1 > 15) ISSUE_R1(f1, cr1);
        else { _Pragma("unroll") for (int k_ = 0; k_ < 8; ++k_) f1[k_] = (uintx2){0u,0u}; }
      } else {
        _Pragma("unroll") for (int k_ = 0; k_ < 8; ++k_){ f0[k_] = (uintx2){0u,0u}; f1[k_] = (uintx2){0u,0u}; }
      }

      // group bookkeeping (overlaps with in-flight loads)
      int g = batch[v];
      if (g != curg){
        if (curg >= 0){
          atomicAdd(&poolS[curg*128 + chbase],     p0);
          atomicAdd(&poolS[curg*128 + chbase + 1], p1);
        }
        p0 = 0.f; p1 = 0.f; curg = g;
      }

      float a0 = 0.f, a1 = 0.f, a2 = 0.f, a3 = 0.f;

      // 3) consume current node's in-flight rounds (issued one node ago)
      CONSUME8(e0);
      if (cv0 > 15) CONSUME8(e1);
      if (cv0 > 31){
        // rare (P ~ 1e-4): sequential paired tail over slots 31..cv0-1
        for (int j = 31; j < cv0; j += 2){
          int uA = __builtin_amdgcn_readlane(cr0, j);
          int uB = (j + 1 < cv0) ? __builtin_amdgcn_readlane(cr0, j + 1) : NNODES;
          int u  = sel ? uB : uA;
          uintx2 dd = H2[(uint_t)u*32u + m];
          a0 += lo16(dd.x); a1 += hi16(dd.x);
          a2 += lo16(dd.y); a3 += hi16(dd.y);
        }
      }

      // 4) combine half-wave series: s = lowerA + upperB per channel
      float s0 = a0 + __shfl_xor(a0, 32, 64);
      float s1 = a1 + __shfl_xor(a1, 32, 64);
      float s2 = a2 + __shfl_xor(a2, 32, 64);
      float s3 = a3 + __shfl_xor(a3, 32, 64);

      // 5) epilogue
      float dvv = rsqrtf((float)(cv0 + 1));
      float r0 = fmaxf(s0*dvv + bbv[0], 0.f);
      float r1 = fmaxf(s1*dvv + bbv[1], 0.f);
      float r2 = fmaxf(s2*dvv + bbv[2], 0.f);
      float r3 = fmaxf(s3*dvv + bbv[3], 0.f);
      if constexpr (WR){
        if (lane < 32){
          uintx2 wv;
          wv.x = pkbf(r0, r1);
          wv.y = pkbf(r2, r3);
          R2[(uint_t)v*32u + m] = wv;
        }
      }
      float cA = sel ? r2 : r0;
      float cB = sel ? r3 : r1;
      ss0 += cA; ss1 += cB;
      sq0 += cA*cA; sq1 += cB*cB;
      p0 += cA; p1 += cB;

      // 6) rotate pipeline state
      cr0 = cr1; cv0 = cv1;
      cr1 = cr2; cv1 = cv2;
      #pragma unroll
      for (int k_ = 0; k_ < 8; ++k_){ e0[k_] = f0[k_]; e1[k_] = f1[k_]; }
    }
  }

  if (curg >= 0){
    atomicAdd(&poolS[curg*128 + chbase],     p0);
    atomicAdd(&poolS[curg*128 + chbase + 1], p1);
  }
  atomicAdd(&bsum[chbase],     ss0);
  atomicAdd(&bsum[chbase + 1], ss1);
  atomicAdd(&bsq[chbase],      sq0);
  atomicAdd(&bsq[chbase + 1],  sq1);
  __syncthreads();
  if (threadIdx.x < 128){
    atomicAdd(&chansum[threadIdx.x],   bsum[threadIdx.x]);
    atomicAdd(&chansumsq[threadIdx.x], bsq[threadIdx.x]);
  }
}

// ---- final: per-graph output for all 3 layers; BN affine computed inline;
//      per-graph node count via binary search on sorted batch ----
__global__ void k_final(const float* __restrict__ poolS,
                        const int* __restrict__ batch,
                        const float* __restrict__ chanstats,   // 3 layers x [sum(128), sumsq(128)]
                        const float* __restrict__ g0, const float* __restrict__ t0,
                        const float* __restrict__ g1, const float* __restrict__ t1,
                        const float* __restrict__ g2, const float* __restrict__ t2,
                        float* __restrict__ out){
  __shared__ int s_n[2];
  int g = blockIdx.x, c = threadIdx.x;
  if (c < 2){
    int target = g + c;
    int lo = 0, hi = NNODES;
    while (lo < hi){
      int mid = (lo + hi) >> 1;
      if (batch[mid] < target) lo = mid + 1; else hi = mid;
    }
    s_n[c] = lo;
  }
  __syncthreads();
  float n = (float)(s_n[1] - s_n[0]);

  const float* gam[3] = {g0, g1, g2};
  const float* bet[3] = {t0, t1, t2};
  const float invN = 1.0f / (float)NNODES;
  #pragma unroll
  for (int i = 0; i < 3; ++i){
    float mu  = chanstats[i*256 + c] * invN;
    float var = chanstats[i*256 + 128 + c] * invN - mu*mu;
    float a = gam[i][c] * rsqrtf(var + EPSBN);
    float cc = bet[i][c] - mu*a;
    float v = a * poolS[((size_t)i*NGRAPH + g)*128 + c] + n * cc;
    out[(size_t)g*384 + i*128 + c] = v;
  }
}

extern "C" void kernel_launch(void* const* d_in, const int* in_sizes, int n_in,
                              void* d_out, int out_size, void* d_ws, size_t ws_size,
                              hipStream_t stream){
  (void)in_sizes; (void)n_in; (void)out_size; (void)ws_size;

  const float* x     = (const float*)d_in[0];
  const int*   ei    = (const int*)d_in[1];
  const int*   batch = (const int*)d_in[2];
  const float* Wp[3] = {(const float*)d_in[3], (const float*)d_in[7],  (const float*)d_in[11]};
  const float* bp[3] = {(const float*)d_in[4], (const float*)d_in[8],  (const float*)d_in[12]};
  const float* gp[3] = {(const float*)d_in[5], (const float*)d_in[9],  (const float*)d_in[13]};
  const float* tp[3] = {(const float*)d_in[6], (const float*)d_in[10], (const float*)d_in[14]};
  const int* srcp = ei;
  const int* dstp = ei + NEDGES;

  char* w = (char*)d_ws;
  size_t off = 0;
  auto take = [&](size_t bytes) -> char* {
    char* p = w + off;
    off += (bytes + 511) & ~(size_t)511;
    return p;
  };
  int*      cnt       = (int*)take((size_t)NNODES*4);
  int*      colx      = (int*)take((size_t)NNODES*DEGCAP*4);
  ushort_t* hs        = (ushort_t*)take((size_t)(NNODES+1)*128*2);  // +1 zero row for gather padding
  ushort_t* rbuf      = (ushort_t*)take((size_t)NNODES*128*2);   // also aliased as ebuf pre-agg0
  ushort_t* WT        = (ushort_t*)take(128*136*2);
  float*    Kv        = (float*)take(128*4);
  // single contiguous zero region: gBucket | chanstats | poolS
  const size_t ZB_GB = (size_t)NBUCK*16*4;            // 32768
  const size_t ZB_CS = 3*256*4;                       // 3072
  const size_t ZB_PS = (size_t)3*NGRAPH*128*4;        // 786432
  char* zbase = take(ZB_GB + ZB_CS + ZB_PS);
  int*   gBucket   = (int*)zbase;
  float* chanstats = (float*)(zbase + ZB_GB);
  float* poolS     = (float*)(zbase + ZB_GB + ZB_CS);

  // ebuf aliases rbuf: ebuf consumed by k_p2 before agg0 first writes rbuf.
  int2* ebuf = (int2*)rbuf;   // needs NBUCK*BCAP*8 = 19.9 MB <= 25.6 MB

  hipMemsetAsync(zbase, 0, ZB_GB + ZB_CS + ZB_PS, stream);

  // phase 1: bucket edges
  k_p1<<<P1_BLOCKS, 256, 0, stream>>>(srcp, dstp, gBucket, ebuf);
  // phase 2: place colx, write cnt, pad colx (to 15 or 31)
  k_p2<<<NBUCK, 256, 0, stream>>>(ebuf, gBucket, colx, cnt);
  // GEMM0 with normalization folded into epilogue; also zero-inits hs pad row
  k_gemm0<<<GEMM_BLOCKS, 256, 0, stream>>>(x, Wp[0], cnt, hs);

  // layer 0
  k_agg<true><<<AGG_BLOCKS, 256, 0, stream>>>(hs, cnt, colx, bp[0], batch, rbuf,
                                              poolS, chanstats, chanstats + 128);
  k_fold<<<128, 128, 0, stream>>>(Wp[1], chanstats, chanstats + 128,
                                  gp[0], tp[0], WT, Kv);
  // layer 1
  k_gemm<<<GEMM_BLOCKS, 256, 0, stream>>>(rbuf, WT, Kv, cnt, hs);
  k_agg<true><<<AGG_BLOCKS, 256, 0, stream>>>(hs, cnt, colx, bp[1], batch, rbuf,
                                              poolS + (size_t)NGRAPH*128,
                                              chanstats + 256, chanstats + 256 + 128);
  k_fold<<<128, 128, 0, stream>>>(Wp[2], chanstats + 256, chanstats + 256 + 128,
                                  gp[1], tp[1], WT, Kv);
  // layer 2
  k_gemm<<<GEMM_BLOCKS, 256, 0, stream>>>(rbuf, WT, Kv, cnt, hs);
  k_agg<false><<<AGG_BLOCKS, 256, 0, stream>>>(hs, cnt, colx, bp[2], batch, rbuf,
                                               poolS + (size_t)2*NGRAPH*128,
                                               chanstats + 512, chanstats + 512 + 128);

  k_final<<<NGRAPH, 128, 0, stream>>>(poolS, batch, chanstats,
                                      gp[0], tp[0], gp[1], tp[1], gp[2], tp[2],
                                      (float*)d_out);
}